// Round 2
// 319.976 us; speedup vs baseline: 1.0931x; 1.0931x over previous
//
#include <hip/hip_runtime.h>
#include <math.h>

#define BB 32768
#define DD 512
#define CC 527
#define NCOLP 576   // padded W cols: 36 tiles of 16 -> uniform 9 tiles per col-group
#define BM 32       // rows per block (2 row-groups x 16)
#define ZST 532     // LDS z row stride (floats); 532*4 = 2128 = 16B-aligned rows

typedef __attribute__((ext_vector_type(8))) short bf16x8;
typedef __attribute__((ext_vector_type(4))) short bf16x4;
typedef __attribute__((ext_vector_type(4))) float f32x4;
typedef f32x4 f32x4u __attribute__((aligned(4)));   // y rows are only 4B-aligned (527 odd)

// Named-SSA accumulators (R6 lesson: f32x4 arrays never promote -> scratch).
#define FJ(OP) OP(0) OP(1) OP(2) OP(3) OP(4) OP(5) OP(6) OP(7) OP(8)
#define FT(OP) OP(0) OP(1) OP(2) OP(3) OP(4) OP(5) OP(6) OP(7)
#define E4(OP) OP(0) OP(1) OP(2) OP(3)

#if __has_builtin(__builtin_amdgcn_exp2f)
#define EXP2F(v) __builtin_amdgcn_exp2f(v)
#else
#define EXP2F(v) exp2f(v)
#endif
#if __has_builtin(__builtin_amdgcn_logf)
#define LOG2F(v) __builtin_amdgcn_logf(v)
#else
#define LOG2F(v) __log2f(v)
#endif

__device__ __forceinline__ short f2bf(float f) {  // fp32 -> bf16 RNE
  unsigned u = __float_as_uint(f);
  u += 0x7fffu + ((u >> 16) & 1u);
  return (short)(u >> 16);
}
__device__ __forceinline__ bf16x8 pack8(f32x4 a, f32x4 b) {
  bf16x8 v;
  v[0]=f2bf(a.x); v[1]=f2bf(a.y); v[2]=f2bf(a.z); v[3]=f2bf(a.w);
  v[4]=f2bf(b.x); v[5]=f2bf(b.y); v[6]=f2bf(b.z); v[7]=f2bf(b.w);
  return v;
}

// 16-lane (DPP row) reductions: 4 x row_ror adds, pure VALU, no LDS pipe.
// row_ror:n = dpp_ctrl 0x120|n; rotations 1,2,4,8 give every lane the row total.
__device__ __forceinline__ int dppadd16(int v) {
  v += __builtin_amdgcn_update_dpp(0, v, 0x121, 0xf, 0xf, false);
  v += __builtin_amdgcn_update_dpp(0, v, 0x122, 0xf, 0xf, false);
  v += __builtin_amdgcn_update_dpp(0, v, 0x124, 0xf, 0xf, false);
  v += __builtin_amdgcn_update_dpp(0, v, 0x128, 0xf, 0xf, false);
  return v;
}
__device__ __forceinline__ float dppmax16(float v) {
  v = fmaxf(v, __int_as_float(__builtin_amdgcn_update_dpp(0, __float_as_int(v), 0x121, 0xf, 0xf, false)));
  v = fmaxf(v, __int_as_float(__builtin_amdgcn_update_dpp(0, __float_as_int(v), 0x122, 0xf, 0xf, false)));
  v = fmaxf(v, __int_as_float(__builtin_amdgcn_update_dpp(0, __float_as_int(v), 0x124, 0xf, 0xf, false)));
  v = fmaxf(v, __int_as_float(__builtin_amdgcn_update_dpp(0, __float_as_int(v), 0x128, 0xf, 0xf, false)));
  return v;
}
__device__ __forceinline__ float dppmin16(float v) {
  v = fminf(v, __int_as_float(__builtin_amdgcn_update_dpp(0, __float_as_int(v), 0x121, 0xf, 0xf, false)));
  v = fminf(v, __int_as_float(__builtin_amdgcn_update_dpp(0, __float_as_int(v), 0x122, 0xf, 0xf, false)));
  v = fminf(v, __int_as_float(__builtin_amdgcn_update_dpp(0, __float_as_int(v), 0x124, 0xf, 0xf, false)));
  v = fminf(v, __int_as_float(__builtin_amdgcn_update_dpp(0, __float_as_int(v), 0x128, 0xf, 0xf, false)));
  return v;
}

// Block = 512 thr = 8 waves = 2 row-groups x 4 col-groups. GEMM: wave = 16 rows x
// 9 interleaved col-tiles, barrier-free, B streams from L2. Epilogue: z -> LDS,
// one barrier, then ONE ROW PER 16-LANE GROUP (quad): lane holds 9 f32x4 chunks
// (cols 64t+4cl+e). Bisection count-reduce = 4 DPP row_ror adds (VALU latency)
// instead of a 6-step cross-wave ds_swizzle butterfly; bracket = per-row min/max.
template<bool PRE>
__global__ __launch_bounds__(512, 4)
void fused_mfma_bce_topk(const float* __restrict__ x, const float* __restrict__ y,
                         const float* __restrict__ W, const short* __restrict__ Wbf,
                         const float* __restrict__ bias, const float* __restrict__ pw,
                         float* __restrict__ accum) {
  __shared__ float zs[BM][ZST];   // 68,096 B -> 2 blocks/CU
  __shared__ float redL[8], redS[8];

  const int tid  = threadIdx.x;
  const int w    = tid >> 6, lane = tid & 63;
  const int cl   = lane & 15, quad = lane >> 4;
  const int rg   = w >> 2, cg = w & 3;
  const int row0 = blockIdx.x * BM;

#define DECL(j) f32x4 A##j = (f32x4){0.f, 0.f, 0.f, 0.f};
  FJ(DECL)
#undef DECL

  // ---------------- barrier-free MFMA GEMM over K = 512 ----------------
  const float* ax = x + (size_t)(row0 + rg * 16 + cl) * DD + quad * 8;
  f32x4 pa0 = *(const f32x4*)(ax);
  f32x4 pa1 = *(const f32x4*)(ax + 4);

  for (int k0 = 0; k0 < DD; k0 += 32) {
    bf16x8 af = pack8(pa0, pa1);
    if (k0 + 32 < DD) {
      pa0 = *(const f32x4*)(ax + k0 + 32);
      pa1 = *(const f32x4*)(ax + k0 + 36);
    }
    if (PRE) {
#define MFS(j) { \
      bf16x8 bfr = *(const bf16x8*)(Wbf + (size_t)((cg + 4*(j)) * 16 + cl) * DD + k0 + quad * 8); \
      A##j = __builtin_amdgcn_mfma_f32_16x16x32_bf16(af, bfr, A##j, 0, 0, 0); }
      FJ(MFS)
#undef MFS
    } else {
#define MFSF(j) { \
      int col = (cg + 4*(j)) * 16 + cl; \
      bf16x8 bfr = {0,0,0,0,0,0,0,0}; \
      if (col < CC) { \
        const float* wp = W + (size_t)col * DD + k0 + quad * 8; \
        bfr = pack8(*(const f32x4*)wp, *(const f32x4*)(wp + 4)); \
      } \
      A##j = __builtin_amdgcn_mfma_f32_16x16x32_bf16(af, bfr, A##j, 0, 0, 0); }
      FJ(MFSF)
#undef MFSF
    }
  }

  // ---------------- epilogue geometry + y prefetch (issued EARLY) ----------
  const int erow = w * 4 + quad;                 // 0..31
  const float* yrow = y + (size_t)(row0 + erow) * CC;
  const int cb = 4 * cl;                         // 0..60

  // y prefetch BEFORE the z->LDS writes and the barrier: global-load latency
  // hides under 36 ds_writes + barrier drain. Plain (cached) loads: x+y fit in
  // the 256 MB L3, so no nontemporal hint.
#define LY(t) f32x4 Y##t = (f32x4)(*(const f32x4u*)(yrow + 64*(t) + cb));
  FT(LY)
#undef LY
#define LY8(e) float y8_##e = (512 + cb + (e) < CC) ? yrow[512 + cb + (e)] : 0.f;
  E4(LY8)
#undef LY8

  // ---------------- z (+bias) -> LDS ----------------
  // C/D layout: col = (cg+4j)*16 + cl, local row = rg*16 + quad*4 + r
#define WRZ(j) { \
    int col = (cg + 4*(j)) * 16 + cl; \
    if (col < 528) { \
      float bt = (col < CC) ? bias[col] : 0.f; \
      int rr0 = rg * 16 + quad * 4; \
      zs[rr0 + 0][col] = A##j[0] + bt; \
      zs[rr0 + 1][col] = A##j[1] + bt; \
      zs[rr0 + 2][col] = A##j[2] + bt; \
      zs[rr0 + 3][col] = A##j[3] + bt; \
    } }
  FJ(WRZ)
#undef WRZ

  __syncthreads();

  // z fragments: 16B-aligned ds_read_b128, bank-uniform per group.
#define RDZ(t) f32x4 ZC##t = *(const f32x4*)&zs[erow][64*(t) + cb];
  FT(RDZ)
#undef RDZ
  f32x4 ZC8;
  {
    const int c8 = 512 + cb;
    if (c8 < CC) {
      f32x4 zt = *(const f32x4*)&zs[erow][c8];
#define SETZ8(e) ZC8[e] = (c8 + (e) < CC) ? zt[e] : -1e30f;
      E4(SETZ8)
#undef SETZ8
    } else {
      ZC8 = (f32x4){-1e30f, -1e30f, -1e30f, -1e30f};
    }
  }

  // loss + positive mask (pw is tiny & cache-resident; 16B vector loads)
  unsigned ym0 = 0, ym1 = 0;
  float lossloc = 0.f;
#define LOSSE(t, e) { \
    float z = ZC##t[e]; float yv = Y##t[e]; \
    float l1 = LOG2F(1.f + EXP2F(fabsf(z) * -1.4426950408889634f)) * 0.6931471805599453f; \
    float sp = fmaxf(z, 0.f) + l1; \
    lossloc += PWt[e] * yv * (sp - z) + (1.f - yv) * sp; \
    if (yv > 0.5f) ym0 |= (1u << (4*(t)+(e))); }
#define LOSST(t) { \
    f32x4 PWt = *(const f32x4*)(pw + 64*(t) + cb); \
    LOSSE(t,0) LOSSE(t,1) LOSSE(t,2) LOSSE(t,3) }
  FT(LOSST)
#undef LOSST
#undef LOSSE
#define LOSS8(e) { \
    if (512 + cb + (e) < CC) { \
      float z = ZC8[e]; float yv = y8_##e; \
      float pv = pw[512 + cb + (e)]; \
      float l1 = LOG2F(1.f + EXP2F(fabsf(z) * -1.4426950408889634f)) * 0.6931471805599453f; \
      float sp = fmaxf(z, 0.f) + l1; \
      lossloc += pv * yv * (sp - z) + (1.f - yv) * sp; \
      if (yv > 0.5f) ym1 |= (1u << (e)); } }
  E4(LOSS8)
#undef LOSS8

  // per-row bracket: min over cols 0..511 (all-valid; k << 512 so it's a safe
  // lower bound for the k-th largest), max over everything (dummies are -1e30).
  float mx = -1e30f, mn = 1e30f;
#define MMX(t) { \
    mx = fmaxf(mx, fmaxf(fmaxf(ZC##t[0], ZC##t[1]), fmaxf(ZC##t[2], ZC##t[3]))); \
    mn = fminf(mn, fminf(fminf(ZC##t[0], ZC##t[1]), fminf(ZC##t[2], ZC##t[3]))); }
  FT(MMX)
#undef MMX
  mx = fmaxf(mx, fmaxf(fmaxf(ZC8[0], ZC8[1]), fmaxf(ZC8[2], ZC8[3])));
  mx = dppmax16(mx);
  mn = dppmin16(mn);

  const int kk = dppadd16(__popc(ym0) + __popc(ym1));

  // bisection: per-group (16-lane) uniform; early exit is wave-level.
  float lo = mn, hi = mx, th = 0.f;
  bool fnd = false;
#pragma unroll 1
  for (int it = 0; it < 32; ++it) {
    const float tm = 0.5f * (lo + hi);
    int c0 = 0, c1 = 0, c2 = 0, c3 = 0;
#define CNTT(t) { c0 += ZC##t[0] > tm; c1 += ZC##t[1] > tm; \
                  c2 += ZC##t[2] > tm; c3 += ZC##t[3] > tm; }
    FT(CNTT)
    CNTT(8)
#undef CNTT
    const int c = dppadd16((c0 + c1) + (c2 + c3));
    if (!fnd) {
      if (c == kk)                   { th = tm; fnd = true; }
      else if (tm <= lo || tm >= hi) { th = lo; fnd = true; }
      else if (c > kk)               lo = tm;
      else                           hi = tm;
    }
    if (__all(fnd)) break;
  }
  if (!fnd) th = lo;

  // hits among positives
  int h0 = 0, h1 = 0, h2 = 0, h3 = 0;
#define HITT(t) { \
    h0 += (int)((ym0 >> (4*(t)+0)) & 1u) & (int)(ZC##t[0] > th); \
    h1 += (int)((ym0 >> (4*(t)+1)) & 1u) & (int)(ZC##t[1] > th); \
    h2 += (int)((ym0 >> (4*(t)+2)) & 1u) & (int)(ZC##t[2] > th); \
    h3 += (int)((ym0 >> (4*(t)+3)) & 1u) & (int)(ZC##t[3] > th); }
  FT(HITT)
#undef HITT
  h0 += (int)( ym1       & 1u) & (int)(ZC8[0] > th);
  h1 += (int)((ym1 >> 1) & 1u) & (int)(ZC8[1] > th);
  h2 += (int)((ym1 >> 2) & 1u) & (int)(ZC8[2] > th);
  h3 += (int)((ym1 >> 3) & 1u) & (int)(ZC8[3] > th);
  const int h = dppadd16((h0 + h1) + (h2 + h3));

  float scoreloc = 0.f;
  if (cl == 0) {
    const int hv = h < kk ? h : kk;   // tie/exhaustion clamp
    scoreloc = (float)hv / (float)kk;
  }

  // loss+score: wave butterfly; block: LDS + one atomic per block per output
#pragma unroll
  for (int m = 1; m < 64; m <<= 1) {
    lossloc  += __shfl_xor(lossloc, m, 64);
    scoreloc += __shfl_xor(scoreloc, m, 64);
  }
  if (lane == 0) { redL[w] = lossloc; redS[w] = scoreloc; }
  __syncthreads();
  if (tid == 0) {
    float sl = 0.f, ss = 0.f;
#pragma unroll
    for (int i = 0; i < 8; ++i) { sl += redL[i]; ss += redS[i]; }
    atomicAdd(&accum[0], sl);
    atomicAdd(&accum[1], ss);
  }
}

__global__ void wcvt_kernel(const float* __restrict__ W, short* __restrict__ Wbf,
                            float* __restrict__ ws) {
  if (blockIdx.x == 0 && threadIdx.x == 0) { ws[0] = 0.f; ws[1] = 0.f; }
  int idx = (blockIdx.x * 256 + threadIdx.x) * 4;   // elem in [576*512]
  int row = idx >> 9;
  bf16x4 v = {0, 0, 0, 0};
  if (row < CC) {
    f32x4 f = *(const f32x4*)(W + idx);
    v[0]=f2bf(f.x); v[1]=f2bf(f.y); v[2]=f2bf(f.z); v[3]=f2bf(f.w);
  }
  *(bf16x4*)(Wbf + idx) = v;
}

__global__ void init_ws_kernel(float* ws) {
  ws[0] = 0.f;
  ws[1] = 0.f;
}

__global__ void finalize_kernel(const float* __restrict__ ws, float* __restrict__ out) {
  out[0] = (float)((double)ws[0] / ((double)BB * (double)CC));
  out[1] = (float)((double)ws[1] / (double)BB);
}

extern "C" void kernel_launch(void* const* d_in, const int* in_sizes, int n_in,
                              void* d_out, int out_size, void* d_ws, size_t ws_size,
                              hipStream_t stream) {
  const float* x  = (const float*)d_in[0];
  const float* y  = (const float*)d_in[1];
  const float* W  = (const float*)d_in[2];
  const float* b  = (const float*)d_in[3];
  const float* pw = (const float*)d_in[4];
  float* out = (float*)d_out;
  float* ws  = (float*)d_ws;
  short* Wbf = (short*)((char*)d_ws + 64);

  const size_t need = 64 + (size_t)NCOLP * DD * 2;
  const bool pre = (ws_size >= need);

  if (pre) {
    wcvt_kernel<<<dim3(NCOLP * DD / 1024), dim3(256), 0, stream>>>(W, Wbf, ws);
    fused_mfma_bce_topk<true><<<dim3(BB / BM), dim3(512), 0, stream>>>(
        x, y, W, Wbf, b, pw, ws);
  } else {
    init_ws_kernel<<<dim3(1), dim3(1), 0, stream>>>(ws);
    fused_mfma_bce_topk<false><<<dim3(BB / BM), dim3(512), 0, stream>>>(
        x, y, W, Wbf, b, pw, ws);
  }
  finalize_kernel<<<dim3(1), dim3(1), 0, stream>>>(ws, out);
}

// Round 3
// 250.370 us; speedup vs baseline: 1.3970x; 1.2780x over previous
//
#include <hip/hip_runtime.h>
#include <math.h>

#define BB 32768
#define DD 512
#define CC 527
#define NCOLP 576   // padded W cols in Wbf (layout unchanged; only 33 tiles read)
#define BM 32       // rows per block
#define ZST 532     // LDS z row stride (floats); 532*4 = 2128 = 16B-aligned rows
#define XST 520     // LDS x row stride (bf16): 520*2=1040B, banks uniform for frag reads

typedef __attribute__((ext_vector_type(8))) short bf16x8;
typedef __attribute__((ext_vector_type(4))) short bf16x4;
typedef __attribute__((ext_vector_type(4))) float f32x4;
typedef f32x4 f32x4u __attribute__((aligned(4)));   // y rows are only 4B-aligned (527 odd)

#define FT(OP) OP(0) OP(1) OP(2) OP(3) OP(4) OP(5) OP(6) OP(7)
#define E4(OP) OP(0) OP(1) OP(2) OP(3)
#define TJ4(OP) OP(0) OP(1) OP(2) OP(3)

#if __has_builtin(__builtin_amdgcn_exp2f)
#define EXP2F(v) __builtin_amdgcn_exp2f(v)
#else
#define EXP2F(v) exp2f(v)
#endif
#if __has_builtin(__builtin_amdgcn_logf)
#define LOG2F(v) __builtin_amdgcn_logf(v)
#else
#define LOG2F(v) __log2f(v)
#endif

__device__ __forceinline__ short f2bf(float f) {  // fp32 -> bf16 RNE
  unsigned u = __float_as_uint(f);
  u += 0x7fffu + ((u >> 16) & 1u);
  return (short)(u >> 16);
}
__device__ __forceinline__ bf16x8 pack8(f32x4 a, f32x4 b) {
  bf16x8 v;
  v[0]=f2bf(a.x); v[1]=f2bf(a.y); v[2]=f2bf(a.z); v[3]=f2bf(a.w);
  v[4]=f2bf(b.x); v[5]=f2bf(b.y); v[6]=f2bf(b.z); v[7]=f2bf(b.w);
  return v;
}

// 16-lane (DPP row) reductions: 4 x row_ror adds, pure VALU, no LDS pipe.
__device__ __forceinline__ int dppadd16(int v) {
  v += __builtin_amdgcn_update_dpp(0, v, 0x121, 0xf, 0xf, false);
  v += __builtin_amdgcn_update_dpp(0, v, 0x122, 0xf, 0xf, false);
  v += __builtin_amdgcn_update_dpp(0, v, 0x124, 0xf, 0xf, false);
  v += __builtin_amdgcn_update_dpp(0, v, 0x128, 0xf, 0xf, false);
  return v;
}
__device__ __forceinline__ float dppmax16(float v) {
  v = fmaxf(v, __int_as_float(__builtin_amdgcn_update_dpp(0, __float_as_int(v), 0x121, 0xf, 0xf, false)));
  v = fmaxf(v, __int_as_float(__builtin_amdgcn_update_dpp(0, __float_as_int(v), 0x122, 0xf, 0xf, false)));
  v = fmaxf(v, __int_as_float(__builtin_amdgcn_update_dpp(0, __float_as_int(v), 0x124, 0xf, 0xf, false)));
  v = fmaxf(v, __int_as_float(__builtin_amdgcn_update_dpp(0, __float_as_int(v), 0x128, 0xf, 0xf, false)));
  return v;
}
__device__ __forceinline__ float dppmin16(float v) {
  v = fminf(v, __int_as_float(__builtin_amdgcn_update_dpp(0, __float_as_int(v), 0x121, 0xf, 0xf, false)));
  v = fminf(v, __int_as_float(__builtin_amdgcn_update_dpp(0, __float_as_int(v), 0x122, 0xf, 0xf, false)));
  v = fminf(v, __int_as_float(__builtin_amdgcn_update_dpp(0, __float_as_int(v), 0x124, 0xf, 0xf, false)));
  v = fminf(v, __int_as_float(__builtin_amdgcn_update_dpp(0, __float_as_int(v), 0x128, 0xf, 0xf, false)));
  return v;
}

// Block = 512 thr = 8 waves. Prologue: x tile (32 rows x 512) -> LDS as bf16
// (coalesced dwordx4 loads; pack8 eliminated from the K-loop). GEMM: each wave
// computes BOTH 16-row sets over 4-5 col-tiles (33 tiles cover C=527): each
// B-fragment feeds 2 MFMAs -> per-wave B-load count and B L2-traffic halve.
// A-fragments come from LDS (XST=520 pad -> conflict-free ds_read_b128).
// Epilogue (z->LDS transpose, per-16-lane-group row ownership, DPP bisection)
// unchanged from the verified 213us version. LDS x-region unions with zs.
template<bool PRE>
__global__ __launch_bounds__(512, 4)
void fused_mfma_bce_topk(const float* __restrict__ x, const float* __restrict__ y,
                         const float* __restrict__ W, const short* __restrict__ Wbf,
                         const float* __restrict__ bias, const float* __restrict__ pw,
                         float* __restrict__ accum) {
  __shared__ float zs[BM][ZST];   // 68,096 B; bytes [0, 33280) double as bf16 x-stage
  __shared__ float redL[8], redS[8];

  const int tid  = threadIdx.x;
  const int w    = tid >> 6, lane = tid & 63;
  const int cl   = lane & 15, quad = lane >> 4;
  const int row0 = blockIdx.x * BM;

  // ---------------- x -> LDS as bf16 (coalesced) ----------------
  unsigned short* xs = (unsigned short*)&zs[0][0];   // [BM][XST]
  {
    const float* xblk = x + (size_t)row0 * DD;
#pragma unroll
    for (int i = 0; i < 8; ++i) {
      const int e = i * 2048 + tid * 4;        // f32 element index in 32x512 tile
      f32x4 v = *(const f32x4*)(xblk + e);
      const int r = e >> 9, c = e & 511;
      bf16x4 bv;
      bv[0] = f2bf(v.x); bv[1] = f2bf(v.y); bv[2] = f2bf(v.z); bv[3] = f2bf(v.w);
      *(bf16x4*)(xs + r * XST + c) = bv;       // ds_write_b64, 2-way banks (free)
    }
  }
  __syncthreads();

  // tile ranges: wave 0 -> [0,5), wave w>=1 -> [4w+1, 4w+5); 33 tiles total
  const int t0  = (w == 0) ? 0 : 4 * w + 1;
  const bool nt5 = (w == 0);

#define DECL(j) f32x4 P##j = (f32x4){0.f,0.f,0.f,0.f}; f32x4 Q##j = (f32x4){0.f,0.f,0.f,0.f};
  TJ4(DECL) DECL(4)
#undef DECL

  // ---------------- MFMA GEMM over K = 512 (A from LDS) ----------------
  const unsigned short* xr0 = xs + (size_t)cl * XST + quad * 8;          // rowset 0
  const unsigned short* xr1 = xs + (size_t)(16 + cl) * XST + quad * 8;   // rowset 1

  if (PRE) {
#define WB(j) const short* wb##j = Wbf + (size_t)((t0 + (j)) * 16 + cl) * DD + quad * 8;
    TJ4(WB) WB(4)
#undef WB
#define GSTEP(j) { \
    bf16x8 bfr = *(const bf16x8*)(wb##j + k0); \
    P##j = __builtin_amdgcn_mfma_f32_16x16x32_bf16(a0, bfr, P##j, 0, 0, 0); \
    Q##j = __builtin_amdgcn_mfma_f32_16x16x32_bf16(a1, bfr, Q##j, 0, 0, 0); }
    for (int k0 = 0; k0 < DD; k0 += 32) {
      bf16x8 a0 = *(const bf16x8*)(xr0 + k0);
      bf16x8 a1 = *(const bf16x8*)(xr1 + k0);
      TJ4(GSTEP)
      if (nt5) { GSTEP(4) }
    }
#undef GSTEP
  } else {
#define GSTEPF(j) { \
    int col = (t0 + (j)) * 16 + cl; \
    bf16x8 bfr = {0,0,0,0,0,0,0,0}; \
    if (col < CC) { \
      const float* wp = W + (size_t)col * DD + k0 + quad * 8; \
      bfr = pack8(*(const f32x4*)wp, *(const f32x4*)(wp + 4)); \
    } \
    P##j = __builtin_amdgcn_mfma_f32_16x16x32_bf16(a0, bfr, P##j, 0, 0, 0); \
    Q##j = __builtin_amdgcn_mfma_f32_16x16x32_bf16(a1, bfr, Q##j, 0, 0, 0); }
    for (int k0 = 0; k0 < DD; k0 += 32) {
      bf16x8 a0 = *(const bf16x8*)(xr0 + k0);
      bf16x8 a1 = *(const bf16x8*)(xr1 + k0);
      TJ4(GSTEPF)
      if (nt5) { GSTEPF(4) }
    }
#undef GSTEPF
  }

  // all A-reads done before zs overwrites the x-stage region
  __syncthreads();

  // ---------------- epilogue geometry + y prefetch (issued EARLY) ----------
  const int erow = w * 4 + quad;                 // 0..31
  const float* yrow = y + (size_t)(row0 + erow) * CC;
  const int cb = 4 * cl;                         // 0..60

#define LY(t) f32x4 Y##t = (f32x4)(*(const f32x4u*)(yrow + 64*(t) + cb));
  FT(LY)
#undef LY
#define LY8(e) float y8_##e = (512 + cb + (e) < CC) ? yrow[512 + cb + (e)] : 0.f;
  E4(LY8)
#undef LY8

  // ---------------- z (+bias) -> LDS ----------------
  // C/D layout: col = (t0+j)*16 + cl (<= 527 < ZST), rows quad*4+r (P) / 16+quad*4+r (Q)
#define WRZ(j) { \
    const int col = (t0 + (j)) * 16 + cl; \
    const float bt = (col < CC) ? bias[col] : 0.f; \
    const int rr0 = quad * 4; \
    zs[rr0 + 0][col] = P##j[0] + bt; \
    zs[rr0 + 1][col] = P##j[1] + bt; \
    zs[rr0 + 2][col] = P##j[2] + bt; \
    zs[rr0 + 3][col] = P##j[3] + bt; \
    zs[16 + rr0 + 0][col] = Q##j[0] + bt; \
    zs[16 + rr0 + 1][col] = Q##j[1] + bt; \
    zs[16 + rr0 + 2][col] = Q##j[2] + bt; \
    zs[16 + rr0 + 3][col] = Q##j[3] + bt; }
  TJ4(WRZ)
  if (nt5) { WRZ(4) }
#undef WRZ

  __syncthreads();

  // ---------------- per-16-lane-group epilogue (unchanged) ----------------
#define RDZ(t) f32x4 ZC##t = *(const f32x4*)&zs[erow][64*(t) + cb];
  FT(RDZ)
#undef RDZ
  f32x4 ZC8;
  {
    const int c8 = 512 + cb;
    if (c8 < CC) {
      f32x4 zt = *(const f32x4*)&zs[erow][c8];
#define SETZ8(e) ZC8[e] = (c8 + (e) < CC) ? zt[e] : -1e30f;
      E4(SETZ8)
#undef SETZ8
    } else {
      ZC8 = (f32x4){-1e30f, -1e30f, -1e30f, -1e30f};
    }
  }

  unsigned ym0 = 0, ym1 = 0;
  float lossloc = 0.f;
#define LOSSE(t, e) { \
    float z = ZC##t[e]; float yv = Y##t[e]; \
    float l1 = LOG2F(1.f + EXP2F(fabsf(z) * -1.4426950408889634f)) * 0.6931471805599453f; \
    float sp = fmaxf(z, 0.f) + l1; \
    lossloc += PWt[e] * yv * (sp - z) + (1.f - yv) * sp; \
    if (yv > 0.5f) ym0 |= (1u << (4*(t)+(e))); }
#define LOSST(t) { \
    f32x4 PWt = *(const f32x4*)(pw + 64*(t) + cb); \
    LOSSE(t,0) LOSSE(t,1) LOSSE(t,2) LOSSE(t,3) }
  FT(LOSST)
#undef LOSST
#undef LOSSE
#define LOSS8(e) { \
    if (512 + cb + (e) < CC) { \
      float z = ZC8[e]; float yv = y8_##e; \
      float pv = pw[512 + cb + (e)]; \
      float l1 = LOG2F(1.f + EXP2F(fabsf(z) * -1.4426950408889634f)) * 0.6931471805599453f; \
      float sp = fmaxf(z, 0.f) + l1; \
      lossloc += pv * yv * (sp - z) + (1.f - yv) * sp; \
      if (yv > 0.5f) ym1 |= (1u << (e)); } }
  E4(LOSS8)
#undef LOSS8

  float mx = -1e30f, mn = 1e30f;
#define MMX(t) { \
    mx = fmaxf(mx, fmaxf(fmaxf(ZC##t[0], ZC##t[1]), fmaxf(ZC##t[2], ZC##t[3]))); \
    mn = fminf(mn, fminf(fminf(ZC##t[0], ZC##t[1]), fminf(ZC##t[2], ZC##t[3]))); }
  FT(MMX)
#undef MMX
  mx = fmaxf(mx, fmaxf(fmaxf(ZC8[0], ZC8[1]), fmaxf(ZC8[2], ZC8[3])));
  mx = dppmax16(mx);
  mn = dppmin16(mn);

  const int kk = dppadd16(__popc(ym0) + __popc(ym1));

  float lo = mn, hi = mx, th = 0.f;
  bool fnd = false;
#pragma unroll 1
  for (int it = 0; it < 32; ++it) {
    const float tm = 0.5f * (lo + hi);
    int c0 = 0, c1 = 0, c2 = 0, c3 = 0;
#define CNTT(t) { c0 += ZC##t[0] > tm; c1 += ZC##t[1] > tm; \
                  c2 += ZC##t[2] > tm; c3 += ZC##t[3] > tm; }
    FT(CNTT)
    CNTT(8)
#undef CNTT
    const int c = dppadd16((c0 + c1) + (c2 + c3));
    if (!fnd) {
      if (c == kk)                   { th = tm; fnd = true; }
      else if (tm <= lo || tm >= hi) { th = lo; fnd = true; }
      else if (c > kk)               lo = tm;
      else                           hi = tm;
    }
    if (__all(fnd)) break;
  }
  if (!fnd) th = lo;

  int h0 = 0, h1 = 0, h2 = 0, h3 = 0;
#define HITT(t) { \
    h0 += (int)((ym0 >> (4*(t)+0)) & 1u) & (int)(ZC##t[0] > th); \
    h1 += (int)((ym0 >> (4*(t)+1)) & 1u) & (int)(ZC##t[1] > th); \
    h2 += (int)((ym0 >> (4*(t)+2)) & 1u) & (int)(ZC##t[2] > th); \
    h3 += (int)((ym0 >> (4*(t)+3)) & 1u) & (int)(ZC##t[3] > th); }
  FT(HITT)
#undef HITT
  h0 += (int)( ym1       & 1u) & (int)(ZC8[0] > th);
  h1 += (int)((ym1 >> 1) & 1u) & (int)(ZC8[1] > th);
  h2 += (int)((ym1 >> 2) & 1u) & (int)(ZC8[2] > th);
  h3 += (int)((ym1 >> 3) & 1u) & (int)(ZC8[3] > th);
  const int h = dppadd16((h0 + h1) + (h2 + h3));

  float scoreloc = 0.f;
  if (cl == 0) {
    const int hv = h < kk ? h : kk;   // tie/exhaustion clamp
    scoreloc = (float)hv / (float)kk;
  }

#pragma unroll
  for (int m = 1; m < 64; m <<= 1) {
    lossloc  += __shfl_xor(lossloc, m, 64);
    scoreloc += __shfl_xor(scoreloc, m, 64);
  }
  if (lane == 0) { redL[w] = lossloc; redS[w] = scoreloc; }
  __syncthreads();
  if (tid == 0) {
    float sl = 0.f, ss = 0.f;
#pragma unroll
    for (int i = 0; i < 8; ++i) { sl += redL[i]; ss += redS[i]; }
    atomicAdd(&accum[0], sl);
    atomicAdd(&accum[1], ss);
  }
}

__global__ void wcvt_kernel(const float* __restrict__ W, short* __restrict__ Wbf,
                            float* __restrict__ ws) {
  if (blockIdx.x == 0 && threadIdx.x == 0) { ws[0] = 0.f; ws[1] = 0.f; }
  int idx = (blockIdx.x * 256 + threadIdx.x) * 4;   // elem in [576*512]
  int row = idx >> 9;
  bf16x4 v = {0, 0, 0, 0};
  if (row < CC) {
    f32x4 f = *(const f32x4*)(W + idx);
    v[0]=f2bf(f.x); v[1]=f2bf(f.y); v[2]=f2bf(f.z); v[3]=f2bf(f.w);
  }
  *(bf16x4*)(Wbf + idx) = v;
}

__global__ void init_ws_kernel(float* ws) {
  ws[0] = 0.f;
  ws[1] = 0.f;
}

__global__ void finalize_kernel(const float* __restrict__ ws, float* __restrict__ out) {
  out[0] = (float)((double)ws[0] / ((double)BB * (double)CC));
  out[1] = (float)((double)ws[1] / (double)BB);
}

extern "C" void kernel_launch(void* const* d_in, const int* in_sizes, int n_in,
                              void* d_out, int out_size, void* d_ws, size_t ws_size,
                              hipStream_t stream) {
  const float* x  = (const float*)d_in[0];
  const float* y  = (const float*)d_in[1];
  const float* W  = (const float*)d_in[2];
  const float* b  = (const float*)d_in[3];
  const float* pw = (const float*)d_in[4];
  float* out = (float*)d_out;
  float* ws  = (float*)d_ws;
  short* Wbf = (short*)((char*)d_ws + 64);

  const size_t need = 64 + (size_t)NCOLP * DD * 2;
  const bool pre = (ws_size >= need);

  if (pre) {
    wcvt_kernel<<<dim3(NCOLP * DD / 1024), dim3(256), 0, stream>>>(W, Wbf, ws);
    fused_mfma_bce_topk<true><<<dim3(BB / BM), dim3(512), 0, stream>>>(
        x, y, W, Wbf, b, pw, ws);
  } else {
    init_ws_kernel<<<dim3(1), dim3(1), 0, stream>>>(ws);
    fused_mfma_bce_topk<false><<<dim3(BB / BM), dim3(512), 0, stream>>>(
        x, y, W, Wbf, b, pw, ws);
  }
  finalize_kernel<<<dim3(1), dim3(1), 0, stream>>>(ws, out);
}